// Round 13
// baseline (1268.981 us; speedup 1.0000x reference)
//
#include <hip/hip_runtime.h>
#include <math.h>

typedef __attribute__((ext_vector_type(4))) float f32x4;
typedef __attribute__((ext_vector_type(8))) short bf16x8;

#define DI __device__ __forceinline__

DI unsigned short f32_to_bf16(float f) {
  unsigned int u = __float_as_uint(f);
  u += 0x7FFFu + ((u >> 16) & 1u);   // round-to-nearest-even
  return (unsigned short)(u >> 16);
}

static constexpr float kCode[16] = {
    -1.0f, -0.6961928009986877f, -0.5250730514526367f, -0.39491748809814453f,
    -0.28444138169288635f, -0.18477343022823334f, -0.09105003625154495f, 0.0f,
    0.07958029955625534f, 0.16093020141124725f, 0.24611230194568634f,
    0.33791524171829224f, 0.44070982933044434f, 0.5626170039176941f,
    0.7229568362236023f, 1.0f};

// ---------------------------------------------------------------------------
// NF4 quant-dequant (block=64): 16 lanes/block, float4/lane. Division-free.
// ---------------------------------------------------------------------------
DI void dequant_body(const float* __restrict__ in, unsigned short* __restrict__ out, int i) {
  f32x4 v = reinterpret_cast<const f32x4*>(in)[i];
  float am = fmaxf(fmaxf(fabsf(v.x), fabsf(v.y)), fmaxf(fabsf(v.z), fabsf(v.w)));
  am = fmaxf(am, __shfl_xor(am, 1));
  am = fmaxf(am, __shfl_xor(am, 2));
  am = fmaxf(am, __shfl_xor(am, 4));
  am = fmaxf(am, __shfl_xor(am, 8));
  const float scale = (am == 0.0f) ? 1.0f : am;
  float sb[15];
#pragma unroll
  for (int b = 0; b < 15; ++b)
    sb[b] = (0.5f * (kCode[b] + kCode[b + 1])) * scale;
  unsigned short o[4];
#pragma unroll
  for (int j = 0; j < 4; ++j) {
    const float vj = ((const float*)&v)[j];
    int idx = 0;
#pragma unroll
    for (int b = 0; b < 15; ++b)
      idx += (vj > sb[b]) ? 1 : 0;
    o[j] = f32_to_bf16(kCode[idx] * am);
  }
  reinterpret_cast<ushort4*>(out)[i] = make_ushort4(o[0], o[1], o[2], o[3]);
}

__global__ void __launch_bounds__(256) k_dequant_nf4(
    const float* __restrict__ in, unsigned short* __restrict__ out, int n4) {
  int i = blockIdx.x * 256 + threadIdx.x;
  if (i >= n4) return;
  dequant_body(in, out, i);
}

// merged aux (3-way): x convert + w1 + w2
__global__ void __launch_bounds__(256) k_aux_all(
    const float* __restrict__ x, unsigned short* __restrict__ xb, int n4x,
    const float* __restrict__ w1, unsigned short* __restrict__ w1b,
    const float* __restrict__ w2, unsigned short* __restrict__ w2b, int n4w) {
  int i = blockIdx.x * 256 + threadIdx.x;
  if (i < n4x) {
    f32x4 v = reinterpret_cast<const f32x4*>(x)[i];
    reinterpret_cast<ushort4*>(xb)[i] =
        make_ushort4(f32_to_bf16(v.x), f32_to_bf16(v.y), f32_to_bf16(v.z), f32_to_bf16(v.w));
  } else if (i < n4x + n4w) {
    dequant_body(w1, w1b, i - n4x);
  } else {
    dequant_body(w2, w2b, i - n4x - n4w);
  }
}

// merged aux (4-way): x convert + w1 + w2 + w3 (used when ws_size permits)
__global__ void __launch_bounds__(256) k_aux_all4(
    const float* __restrict__ x, unsigned short* __restrict__ xb, int n4x,
    const float* __restrict__ w1, unsigned short* __restrict__ w1b,
    const float* __restrict__ w2, unsigned short* __restrict__ w2b,
    const float* __restrict__ w3, unsigned short* __restrict__ w3b, int n4w) {
  int i = blockIdx.x * 256 + threadIdx.x;
  if (i < n4x) {
    f32x4 v = reinterpret_cast<const f32x4*>(x)[i];
    reinterpret_cast<ushort4*>(xb)[i] =
        make_ushort4(f32_to_bf16(v.x), f32_to_bf16(v.y), f32_to_bf16(v.z), f32_to_bf16(v.w));
  } else if (i < n4x + n4w) {
    dequant_body(w1, w1b, i - n4x);
  } else if (i < n4x + 2 * n4w) {
    dequant_body(w2, w2b, i - n4x - n4w);
  } else {
    dequant_body(w3, w3b, i - n4x - 2 * n4w);
  }
}

// ---------------------------------------------------------------------------
// GEMM helpers. BK=32, LDS rows = 64B. Element (r,k) at byte
//   r*64 + (((k>>3) ^ ((r>>1)&3))<<4) + (k&7)*2     (round-4 verified)
// Staging: global_load_lds linear; lane l of 1KB unit covers row 16u+(l>>2),
// k-chunk (l&3)^((l>>3)&3). Read: (rowbase+(l&15))*64 + ((l>>4)^((l>>1)&3))<<4
// -> conflict-free (SQ_LDS_BANK_CONFLICT == 0, rounds 4/5/8/9/11/12).
// ---------------------------------------------------------------------------
DI void gload16(const void* g, void* l) {
  __builtin_amdgcn_global_load_lds(
      (const __attribute__((address_space(1))) void*)g,
      (__attribute__((address_space(3))) void*)l, 16, 0, 0);
}

DI void barrier_nodrain() {
  asm volatile("" ::: "memory");
  __builtin_amdgcn_s_barrier();
  asm volatile("" ::: "memory");
}

#define WAITV(N) asm volatile("s_waitcnt vmcnt(" #N ")" ::: "memory")

DI float fast_silu(float g) {
  const float e = __builtin_amdgcn_exp2f(g * -1.442695041f);
  return g * __builtin_amdgcn_rcpf(1.0f + e);
}

// ---------------------------------------------------------------------------
// Fused dual GEMM + SwiGLU. BM=256, BN=128, BK=32, 16 waves (4/SIMD):
// waves 0-7 gate (B1), 8-15 up (B2); pair p = w&7 owns 64x64 at
// (wr=p>>1, wc=p&1). 4 LDS bufs x 32KB (A 16K | B1 8K | B2 8K),
// prefetch distance 3, counted vmcnt(4), hoisted wait-ladder.
// mt-stretch XCD swizzle: XCD x runs mt=2x for ii<86 then mt=2x+1 ->
// X panel (2MB) L2-resident; all XCDs share the same nt weight panel (L3).
// ---------------------------------------------------------------------------
__global__ void __launch_bounds__(1024, 4) k_gemm_dual_swiglu(
    const unsigned short* __restrict__ X,
    const unsigned short* __restrict__ W1,
    const unsigned short* __restrict__ W2,
    unsigned short* __restrict__ H) {
  constexpr int K = 4096, N = 11008, NK = K / 32;
  __shared__ char ldsb[131072];

  const int tid = threadIdx.x;
  const int w = tid >> 6, l = tid & 63;

  // mt-stretch XCD swizzle: 1376 blocks = 8 XCD x 172; bijective.
  const int bid = blockIdx.x;
  const int xcd = bid & 7, ii = bid >> 3;   // ii in [0,172)
  const int half = (ii >= 86) ? 1 : 0;
  const int nt = ii - half * 86;            // 0..85 (weight panel)
  const int mt = xcd * 2 + half;            // stable X panel per 86 blocks
  const int m0 = mt * 256, n0 = nt * 128;

  const int p = w & 7;
  const bool isGate = (w < 8);
  const int wr = p >> 1, wc = p & 1;

  // ---- staging: 32 1KB-units, 2 per wave (round-4 verified map) ----
  const int lrow = l >> 2;                              // 0..15
  const int kc8 = (((l & 3) ^ ((l >> 3) & 3)) << 3);    // elem col 0,8,16,24
  const unsigned short* gsrc0;
  const unsigned short* gsrc1;
  int ldst0;
  if (w < 8) {          // A units 2w, 2w+1 (rows m0+32w .. +31)
    gsrc0 = X + (size_t)(m0 + 32 * w + lrow) * K + kc8;
    gsrc1 = X + (size_t)(m0 + 32 * w + 16 + lrow) * K + kc8;
    ldst0 = 2 * w * 1024;
  } else if (w < 12) {  // B1 units
    gsrc0 = W1 + (size_t)(n0 + 32 * (w - 8) + lrow) * K + kc8;
    gsrc1 = W1 + (size_t)(n0 + 32 * (w - 8) + 16 + lrow) * K + kc8;
    ldst0 = 16384 + (w - 8) * 2048;
  } else {              // B2 units
    gsrc0 = W2 + (size_t)(n0 + 32 * (w - 12) + lrow) * K + kc8;
    gsrc1 = W2 + (size_t)(n0 + 32 * (w - 12) + 16 + lrow) * K + kc8;
    ldst0 = 24576 + (w - 12) * 2048;
  }

  // ---- read bases ----
  const int roff = (((l >> 4) ^ ((l >> 1) & 3)) << 4);
  const char* rdA = ldsb + (wr * 64 + (l & 15)) * 64 + roff;
  const char* rdB = ldsb + 16384 + (isGate ? 0 : 8192) +
                    (wc * 64 + (l & 15)) * 64 + roff;

  f32x4 acc[4][4] = {};

#define TILE_BODY(bo) {                                                        \
  bf16x8 a[4], b[4];                                                           \
  _Pragma("unroll") for (int m = 0; m < 4; ++m)                                \
    a[m] = *(const bf16x8*)(rdA + (bo) + m * 1024);                            \
  _Pragma("unroll") for (int n = 0; n < 4; ++n)                                \
    b[n] = *(const bf16x8*)(rdB + (bo) + n * 1024);                            \
  _Pragma("unroll") for (int m = 0; m < 4; ++m)                                \
    _Pragma("unroll") for (int n = 0; n < 4; ++n)                              \
      acc[m][n] = __builtin_amdgcn_mfma_f32_16x16x32_bf16(a[m], b[n], acc[m][n], 0, 0, 0); }

  // prologue: stage tiles 0,1,2
  gload16(gsrc0, ldsb + ldst0);               gload16(gsrc1, ldsb + ldst0 + 1024);
  gload16(gsrc0 + 32, ldsb + 32768 + ldst0);  gload16(gsrc1 + 32, ldsb + 32768 + ldst0 + 1024);
  gload16(gsrc0 + 64, ldsb + 65536 + ldst0);  gload16(gsrc1 + 64, ldsb + 65536 + ldst0 + 1024);
  const unsigned short* pg0 = gsrc0 + 96;     // tile t+3 cursor
  const unsigned short* pg1 = gsrc1 + 96;
  WAITV(4);
  barrier_nodrain();

  int t = 0;
  for (; t + 3 < NK; ++t) {              // branchless main loop
    const int bo = (t & 3) << 15;
    const int bs = ((t + 3) & 3) << 15;
    gload16(pg0, ldsb + bs + ldst0);
    gload16(pg1, ldsb + bs + ldst0 + 1024);
    pg0 += 32; pg1 += 32;
    TILE_BODY(bo);
    WAITV(4); barrier_nodrain();
  }
  // tail: t = NK-3, NK-2, NK-1 (no staging)
  TILE_BODY((t & 3) << 15); WAITV(2); barrier_nodrain(); ++t;
  TILE_BODY((t & 3) << 15); WAITV(0); barrier_nodrain(); ++t;
  TILE_BODY((t & 3) << 15);
#undef TILE_BODY

  // ---- epilogue: pairwise f32 exchange (m-split), balanced stores ----
  barrier_nodrain();  // staging LDS now dead for ALL waves
  char* xch = ldsb + p * 16384 + (isGate ? 0 : 8192);
  // gate writes its m=2,3 frags; up writes its m=0,1 frags
#pragma unroll
  for (int m2 = 0; m2 < 2; ++m2)
#pragma unroll
    for (int n = 0; n < 4; ++n) {
      const int m = isGate ? (m2 + 2) : m2;
      *(f32x4*)(xch + ((m2 * 4 + n) * 64 + l) * 16) = acc[m][n];
    }
  barrier_nodrain();
  const char* oxch = ldsb + p * 16384 + (isGate ? 8192 : 0);
  const int er = (l >> 4) * 4, ec = l & 15;
#pragma unroll
  for (int m2 = 0; m2 < 2; ++m2)
#pragma unroll
    for (int n = 0; n < 4; ++n) {
      const int mk = isGate ? m2 : (m2 + 2);   // rows this wave stores
      f32x4 other = *(const f32x4*)(oxch + ((m2 * 4 + n) * 64 + l) * 16);
#pragma unroll
      for (int j = 0; j < 4; ++j) {
        const float g_ = isGate ? acc[mk][n][j] : other[j];
        const float u_ = isGate ? other[j] : acc[mk][n][j];
        const float s = fast_silu(g_);
        const int row = m0 + wr * 64 + mk * 16 + er + j;
        const int col = n0 + wc * 64 + n * 16 + ec;
        H[(size_t)row * N + col] = f32_to_bf16(s * u_);
      }
    }
}

// ---------------------------------------------------------------------------
// Output GEMM. BM=BN=256, BK=32, 16 waves (4M x 4N), per-wave 64x64.
// 4 LDS bufs x 32KB (A 16K | B 16K), prefetch 3, hoisted ladder.
// mt-stretch XCD swizzle. H x W3^T -> Out f32.
// ---------------------------------------------------------------------------
__global__ void __launch_bounds__(1024, 4) k_gemm_out(
    const unsigned short* __restrict__ Hm,
    const unsigned short* __restrict__ W3,
    float* __restrict__ Out) {
  constexpr int K = 11008, N = 4096, NK = K / 32;   // NK = 344
  __shared__ char ldsb[131072];

  const int tid = threadIdx.x;
  const int w = tid >> 6, l = tid & 63;

  // mt-stretch XCD swizzle: 256 blocks = 8 XCD x 32; bijective.
  const int bid = blockIdx.x;
  const int xcd = bid & 7, ii = bid >> 3;   // ii in [0,32)
  const int half = (ii >= 16) ? 1 : 0;
  const int nt = ii - half * 16;            // 0..15
  const int mt = xcd * 2 + half;            // stable H panel per 16 blocks
  const int m0 = mt * 256, n0 = nt * 256;

  const int wr = w >> 2, wc = w & 3;

  const int lrow = l >> 2;
  const int kc8 = (((l & 3) ^ ((l >> 3) & 3)) << 3);
  const unsigned short* gsrc0;
  const unsigned short* gsrc1;
  int ldst0;
  if (w < 8) {          // A units
    gsrc0 = Hm + (size_t)(m0 + 32 * w + lrow) * K + kc8;
    gsrc1 = Hm + (size_t)(m0 + 32 * w + 16 + lrow) * K + kc8;
    ldst0 = 2 * w * 1024;
  } else {              // B units
    gsrc0 = W3 + (size_t)(n0 + 32 * (w - 8) + lrow) * K + kc8;
    gsrc1 = W3 + (size_t)(n0 + 32 * (w - 8) + 16 + lrow) * K + kc8;
    ldst0 = 16384 + (w - 8) * 2048;
  }

  const int roff = (((l >> 4) ^ ((l >> 1) & 3)) << 4);
  const char* rdA = ldsb + (wr * 64 + (l & 15)) * 64 + roff;
  const char* rdB = ldsb + 16384 + (wc * 64 + (l & 15)) * 64 + roff;

  f32x4 acc[4][4] = {};

#define TILE_BODY(bo) {                                                        \
  bf16x8 a[4], b[4];                                                           \
  _Pragma("unroll") for (int m = 0; m < 4; ++m)                                \
    a[m] = *(const bf16x8*)(rdA + (bo) + m * 1024);                            \
  _Pragma("unroll") for (int n = 0; n < 4; ++n)                                \
    b[n] = *(const bf16x8*)(rdB + (bo) + n * 1024);                            \
  _Pragma("unroll") for (int m = 0; m < 4; ++m)                                \
    _Pragma("unroll") for (int n = 0; n < 4; ++n)                              \
      acc[m][n] = __builtin_amdgcn_mfma_f32_16x16x32_bf16(a[m], b[n], acc[m][n], 0, 0, 0); }

  gload16(gsrc0, ldsb + ldst0);               gload16(gsrc1, ldsb + ldst0 + 1024);
  gload16(gsrc0 + 32, ldsb + 32768 + ldst0);  gload16(gsrc1 + 32, ldsb + 32768 + ldst0 + 1024);
  gload16(gsrc0 + 64, ldsb + 65536 + ldst0);  gload16(gsrc1 + 64, ldsb + 65536 + ldst0 + 1024);
  const unsigned short* pg0 = gsrc0 + 96;
  const unsigned short* pg1 = gsrc1 + 96;
  WAITV(4);
  barrier_nodrain();

  int t = 0;
  for (; t + 3 < NK; ++t) {
    const int bo = (t & 3) << 15;
    const int bs = ((t + 3) & 3) << 15;
    gload16(pg0, ldsb + bs + ldst0);
    gload16(pg1, ldsb + bs + ldst0 + 1024);
    pg0 += 32; pg1 += 32;
    TILE_BODY(bo);
    WAITV(4); barrier_nodrain();
  }
  TILE_BODY((t & 3) << 15); WAITV(2); barrier_nodrain(); ++t;
  TILE_BODY((t & 3) << 15); WAITV(0); barrier_nodrain(); ++t;
  TILE_BODY((t & 3) << 15);
#undef TILE_BODY

  const int er = (l >> 4) * 4, ec = l & 15;
#pragma unroll
  for (int m = 0; m < 4; ++m)
#pragma unroll
    for (int n = 0; n < 4; ++n) {
      const int row = m0 + wr * 64 + m * 16 + er;
      const int col = n0 + wc * 64 + n * 16 + ec;
      float* ptr = Out + (size_t)row * N + col;
#pragma unroll
      for (int j = 0; j < 4; ++j) ptr[(size_t)j * N] = acc[m][n][j];
    }
}

// ---------------------------------------------------------------------------
extern "C" void kernel_launch(void* const* d_in, const int* in_sizes, int n_in,
                              void* d_out, int out_size, void* d_ws, size_t ws_size,
                              hipStream_t stream) {
  const float* x  = (const float*)d_in[0];   // [2,2048,4096] -> [4096][4096]
  const float* w1 = (const float*)d_in[1];   // [11008,4096]
  const float* w2 = (const float*)d_in[2];   // [11008,4096]
  const float* w3 = (const float*)d_in[3];   // [4096,11008]
  float* out = (float*)d_out;

  char* ws = (char*)d_ws;
  unsigned short* xb  = (unsigned short*)(ws);                // 32 MiB
  unsigned short* w1b = (unsigned short*)(ws + 33554432);     // 86 MiB
  unsigned short* w2b = (unsigned short*)(ws + 123731968);    // 86 MiB
  unsigned short* hb  = (unsigned short*)(ws + 213909504);    // 86 MiB

  const int N4X = 4096 * 4096 / 4;           // 4,194,304
  const int NW  = 11008 * 4096 / 4;          // 11,272,192

  const size_t W3B_OFF = 304087040;          // hb end
  const bool sep_w3 = (ws_size >= W3B_OFF + 90177536);

  if (sep_w3) {
    unsigned short* w3b = (unsigned short*)(ws + W3B_OFF);
    const int AUX_BLOCKS = (N4X + 3 * NW) / 256;
    k_aux_all4<<<AUX_BLOCKS, 256, 0, stream>>>(x, xb, N4X, w1, w1b, w2, w2b, w3, w3b, NW);
    k_gemm_dual_swiglu<<<1376, 1024, 0, stream>>>(xb, w1b, w2b, hb);
    k_gemm_out<<<256, 1024, 0, stream>>>(hb, w3b, out);
  } else {
    unsigned short* w3b = w1b;  // reuse after gemm1 (stream-ordered)
    const int AUX_BLOCKS = (N4X + 2 * NW) / 256;
    k_aux_all<<<AUX_BLOCKS, 256, 0, stream>>>(x, xb, N4X, w1, w1b, w2, w2b, NW);
    k_gemm_dual_swiglu<<<1376, 1024, 0, stream>>>(xb, w1b, w2b, hb);
    k_dequant_nf4<<<NW / 256, 256, 0, stream>>>(w3, w3b, NW);
    k_gemm_out<<<256, 1024, 0, stream>>>(hb, w3b, out);
  }
}

// Round 14
// 1241.835 us; speedup vs baseline: 1.0219x; 1.0219x over previous
//
#include <hip/hip_runtime.h>
#include <math.h>

typedef __attribute__((ext_vector_type(4))) float f32x4;
typedef __attribute__((ext_vector_type(8))) short bf16x8;

#define DI __device__ __forceinline__

DI unsigned short f32_to_bf16(float f) {
  unsigned int u = __float_as_uint(f);
  u += 0x7FFFu + ((u >> 16) & 1u);   // round-to-nearest-even
  return (unsigned short)(u >> 16);
}

static constexpr float kCode[16] = {
    -1.0f, -0.6961928009986877f, -0.5250730514526367f, -0.39491748809814453f,
    -0.28444138169288635f, -0.18477343022823334f, -0.09105003625154495f, 0.0f,
    0.07958029955625534f, 0.16093020141124725f, 0.24611230194568634f,
    0.33791524171829224f, 0.44070982933044434f, 0.5626170039176941f,
    0.7229568362236023f, 1.0f};

// ---------------------------------------------------------------------------
// NF4 quant-dequant (block=64): 16 lanes/block, float4/lane. Division-free.
// ---------------------------------------------------------------------------
DI void dequant_body(const float* __restrict__ in, unsigned short* __restrict__ out, int i) {
  f32x4 v = reinterpret_cast<const f32x4*>(in)[i];
  float am = fmaxf(fmaxf(fabsf(v.x), fabsf(v.y)), fmaxf(fabsf(v.z), fabsf(v.w)));
  am = fmaxf(am, __shfl_xor(am, 1));
  am = fmaxf(am, __shfl_xor(am, 2));
  am = fmaxf(am, __shfl_xor(am, 4));
  am = fmaxf(am, __shfl_xor(am, 8));
  const float scale = (am == 0.0f) ? 1.0f : am;
  float sb[15];
#pragma unroll
  for (int b = 0; b < 15; ++b)
    sb[b] = (0.5f * (kCode[b] + kCode[b + 1])) * scale;
  unsigned short o[4];
#pragma unroll
  for (int j = 0; j < 4; ++j) {
    const float vj = ((const float*)&v)[j];
    int idx = 0;
#pragma unroll
    for (int b = 0; b < 15; ++b)
      idx += (vj > sb[b]) ? 1 : 0;
    o[j] = f32_to_bf16(kCode[idx] * am);
  }
  reinterpret_cast<ushort4*>(out)[i] = make_ushort4(o[0], o[1], o[2], o[3]);
}

__global__ void __launch_bounds__(256) k_dequant_nf4(
    const float* __restrict__ in, unsigned short* __restrict__ out, int n4) {
  int i = blockIdx.x * 256 + threadIdx.x;
  if (i >= n4) return;
  dequant_body(in, out, i);
}

// merged aux (3-way): x convert + w1 + w2
__global__ void __launch_bounds__(256) k_aux_all(
    const float* __restrict__ x, unsigned short* __restrict__ xb, int n4x,
    const float* __restrict__ w1, unsigned short* __restrict__ w1b,
    const float* __restrict__ w2, unsigned short* __restrict__ w2b, int n4w) {
  int i = blockIdx.x * 256 + threadIdx.x;
  if (i < n4x) {
    f32x4 v = reinterpret_cast<const f32x4*>(x)[i];
    reinterpret_cast<ushort4*>(xb)[i] =
        make_ushort4(f32_to_bf16(v.x), f32_to_bf16(v.y), f32_to_bf16(v.z), f32_to_bf16(v.w));
  } else if (i < n4x + n4w) {
    dequant_body(w1, w1b, i - n4x);
  } else {
    dequant_body(w2, w2b, i - n4x - n4w);
  }
}

// merged aux (4-way): x convert + w1 + w2 + w3 (used when ws_size permits)
__global__ void __launch_bounds__(256) k_aux_all4(
    const float* __restrict__ x, unsigned short* __restrict__ xb, int n4x,
    const float* __restrict__ w1, unsigned short* __restrict__ w1b,
    const float* __restrict__ w2, unsigned short* __restrict__ w2b,
    const float* __restrict__ w3, unsigned short* __restrict__ w3b, int n4w) {
  int i = blockIdx.x * 256 + threadIdx.x;
  if (i < n4x) {
    f32x4 v = reinterpret_cast<const f32x4*>(x)[i];
    reinterpret_cast<ushort4*>(xb)[i] =
        make_ushort4(f32_to_bf16(v.x), f32_to_bf16(v.y), f32_to_bf16(v.z), f32_to_bf16(v.w));
  } else if (i < n4x + n4w) {
    dequant_body(w1, w1b, i - n4x);
  } else if (i < n4x + 2 * n4w) {
    dequant_body(w2, w2b, i - n4x - n4w);
  } else {
    dequant_body(w3, w3b, i - n4x - 2 * n4w);
  }
}

// ---------------------------------------------------------------------------
// GEMM helpers. BK=32, LDS rows = 64B. Element (r,k) at byte
//   r*64 + (((k>>3) ^ ((r>>1)&3))<<4) + (k&7)*2     (round-4 verified)
// Staging: global_load_lds linear; lane l of 1KB unit covers row 16u+(l>>2),
// k-chunk (l&3)^((l>>3)&3). Read: (rowbase+(l&15))*64 + ((l>>4)^((l>>1)&3))<<4
// -> conflict-free (SQ_LDS_BANK_CONFLICT == 0, rounds 4/5/8/9/11/12).
// ---------------------------------------------------------------------------
DI void gload16(const void* g, void* l) {
  __builtin_amdgcn_global_load_lds(
      (const __attribute__((address_space(1))) void*)g,
      (__attribute__((address_space(3))) void*)l, 16, 0, 0);
}

DI void barrier_nodrain() {
  asm volatile("" ::: "memory");
  __builtin_amdgcn_s_barrier();
  asm volatile("" ::: "memory");
}

#define WAITV(N) asm volatile("s_waitcnt vmcnt(" #N ")" ::: "memory")

DI float fast_silu(float g) {
  const float e = __builtin_amdgcn_exp2f(g * -1.442695041f);
  return g * __builtin_amdgcn_rcpf(1.0f + e);
}

// ---------------------------------------------------------------------------
// Fused dual GEMM + SwiGLU. BM=256, BN=128, BK=32, 16 waves (4/SIMD):
// waves 0-7 gate (B1), 8-15 up (B2); pair p = w&7 owns 64x64 at
// (wr=p>>1, wc=p&1). 4 LDS bufs x 32KB (A 16K | B1 8K | B2 8K),
// prefetch distance 3, counted vmcnt(4), hoisted wait-ladder.
// nt-major XCD swizzle (round-12 verified: FETCH 803MB, MfmaUtil 57.7%).
// ---------------------------------------------------------------------------
__global__ void __launch_bounds__(1024, 4) k_gemm_dual_swiglu(
    const unsigned short* __restrict__ X,
    const unsigned short* __restrict__ W1,
    const unsigned short* __restrict__ W2,
    unsigned short* __restrict__ H) {
  constexpr int K = 4096, N = 11008, NK = K / 32;
  __shared__ char ldsb[131072];

  const int tid = threadIdx.x;
  const int w = tid >> 6, l = tid & 63;

  // nt-major XCD swizzle: 1376 blocks = 8 XCD x 172; bijective.
  const int bid = blockIdx.x;
  const int xcd = bid & 7, ii = bid >> 3;   // ii in [0,172)
  const int nt = ii >> 1;                   // 0..85  (weight panel, slow)
  const int mt = xcd * 2 + (ii & 1);        // 0..15  (X panel, 2 per XCD)
  const int m0 = mt * 256, n0 = nt * 128;

  const int p = w & 7;
  const bool isGate = (w < 8);
  const int wr = p >> 1, wc = p & 1;

  // ---- staging: 32 1KB-units, 2 per wave (round-4 verified map) ----
  const int lrow = l >> 2;                              // 0..15
  const int kc8 = (((l & 3) ^ ((l >> 3) & 3)) << 3);    // elem col 0,8,16,24
  const unsigned short* gsrc0;
  const unsigned short* gsrc1;
  int ldst0;
  if (w < 8) {          // A units 2w, 2w+1 (rows m0+32w .. +31)
    gsrc0 = X + (size_t)(m0 + 32 * w + lrow) * K + kc8;
    gsrc1 = X + (size_t)(m0 + 32 * w + 16 + lrow) * K + kc8;
    ldst0 = 2 * w * 1024;
  } else if (w < 12) {  // B1 units
    gsrc0 = W1 + (size_t)(n0 + 32 * (w - 8) + lrow) * K + kc8;
    gsrc1 = W1 + (size_t)(n0 + 32 * (w - 8) + 16 + lrow) * K + kc8;
    ldst0 = 16384 + (w - 8) * 2048;
  } else {              // B2 units
    gsrc0 = W2 + (size_t)(n0 + 32 * (w - 12) + lrow) * K + kc8;
    gsrc1 = W2 + (size_t)(n0 + 32 * (w - 12) + 16 + lrow) * K + kc8;
    ldst0 = 24576 + (w - 12) * 2048;
  }

  // ---- read bases ----
  const int roff = (((l >> 4) ^ ((l >> 1) & 3)) << 4);
  const char* rdA = ldsb + (wr * 64 + (l & 15)) * 64 + roff;
  const char* rdB = ldsb + 16384 + (isGate ? 0 : 8192) +
                    (wc * 64 + (l & 15)) * 64 + roff;

  f32x4 acc[4][4] = {};

#define TILE_BODY(bo) {                                                        \
  bf16x8 a[4], b[4];                                                           \
  _Pragma("unroll") for (int m = 0; m < 4; ++m)                                \
    a[m] = *(const bf16x8*)(rdA + (bo) + m * 1024);                            \
  _Pragma("unroll") for (int n = 0; n < 4; ++n)                                \
    b[n] = *(const bf16x8*)(rdB + (bo) + n * 1024);                            \
  _Pragma("unroll") for (int m = 0; m < 4; ++m)                                \
    _Pragma("unroll") for (int n = 0; n < 4; ++n)                              \
      acc[m][n] = __builtin_amdgcn_mfma_f32_16x16x32_bf16(a[m], b[n], acc[m][n], 0, 0, 0); }

  // prologue: stage tiles 0,1,2
  gload16(gsrc0, ldsb + ldst0);               gload16(gsrc1, ldsb + ldst0 + 1024);
  gload16(gsrc0 + 32, ldsb + 32768 + ldst0);  gload16(gsrc1 + 32, ldsb + 32768 + ldst0 + 1024);
  gload16(gsrc0 + 64, ldsb + 65536 + ldst0);  gload16(gsrc1 + 64, ldsb + 65536 + ldst0 + 1024);
  const unsigned short* pg0 = gsrc0 + 96;     // tile t+3 cursor
  const unsigned short* pg1 = gsrc1 + 96;
  WAITV(4);
  barrier_nodrain();

  int t = 0;
  for (; t + 3 < NK; ++t) {              // branchless main loop
    const int bo = (t & 3) << 15;
    const int bs = ((t + 3) & 3) << 15;
    gload16(pg0, ldsb + bs + ldst0);
    gload16(pg1, ldsb + bs + ldst0 + 1024);
    pg0 += 32; pg1 += 32;
    TILE_BODY(bo);
    WAITV(4); barrier_nodrain();
  }
  // tail: t = NK-3, NK-2, NK-1 (no staging)
  TILE_BODY((t & 3) << 15); WAITV(2); barrier_nodrain(); ++t;
  TILE_BODY((t & 3) << 15); WAITV(0); barrier_nodrain(); ++t;
  TILE_BODY((t & 3) << 15);
#undef TILE_BODY

  // ---- epilogue: pairwise f32 exchange (m-split), balanced stores ----
  barrier_nodrain();  // staging LDS now dead for ALL waves
  char* xch = ldsb + p * 16384 + (isGate ? 0 : 8192);
  // gate writes its m=2,3 frags; up writes its m=0,1 frags
#pragma unroll
  for (int m2 = 0; m2 < 2; ++m2)
#pragma unroll
    for (int n = 0; n < 4; ++n) {
      const int m = isGate ? (m2 + 2) : m2;
      *(f32x4*)(xch + ((m2 * 4 + n) * 64 + l) * 16) = acc[m][n];
    }
  barrier_nodrain();
  const char* oxch = ldsb + p * 16384 + (isGate ? 8192 : 0);
  const int er = (l >> 4) * 4, ec = l & 15;
#pragma unroll
  for (int m2 = 0; m2 < 2; ++m2)
#pragma unroll
    for (int n = 0; n < 4; ++n) {
      const int mk = isGate ? m2 : (m2 + 2);   // rows this wave stores
      f32x4 other = *(const f32x4*)(oxch + ((m2 * 4 + n) * 64 + l) * 16);
#pragma unroll
      for (int j = 0; j < 4; ++j) {
        const float g_ = isGate ? acc[mk][n][j] : other[j];
        const float u_ = isGate ? other[j] : acc[mk][n][j];
        const float s = fast_silu(g_);
        const int row = m0 + wr * 64 + mk * 16 + er + j;
        const int col = n0 + wc * 64 + n * 16 + ec;
        H[(size_t)row * N + col] = f32_to_bf16(s * u_);
      }
    }
}

// ---------------------------------------------------------------------------
// Output GEMM. BM=BN=256, BK=32, 16 waves (4M x 4N), per-wave 64x64.
// 4 LDS bufs x 32KB (A 16K | B 16K), prefetch 3, hoisted ladder.
// nt-major XCD swizzle (round-12 verified). H x W3^T -> Out f32.
// ---------------------------------------------------------------------------
__global__ void __launch_bounds__(1024, 4) k_gemm_out(
    const unsigned short* __restrict__ Hm,
    const unsigned short* __restrict__ W3,
    float* __restrict__ Out) {
  constexpr int K = 11008, N = 4096, NK = K / 32;   // NK = 344
  __shared__ char ldsb[131072];

  const int tid = threadIdx.x;
  const int w = tid >> 6, l = tid & 63;

  const int bid = blockIdx.x;
  const int xcd = bid & 7, ii = bid >> 3;   // ii in [0,32)
  const int nt = ii >> 1;                   // 0..15
  const int mt = xcd * 2 + (ii & 1);        // 0..15
  const int m0 = mt * 256, n0 = nt * 256;

  const int wr = w >> 2, wc = w & 3;

  const int lrow = l >> 2;
  const int kc8 = (((l & 3) ^ ((l >> 3) & 3)) << 3);
  const unsigned short* gsrc0;
  const unsigned short* gsrc1;
  int ldst0;
  if (w < 8) {          // A units
    gsrc0 = Hm + (size_t)(m0 + 32 * w + lrow) * K + kc8;
    gsrc1 = Hm + (size_t)(m0 + 32 * w + 16 + lrow) * K + kc8;
    ldst0 = 2 * w * 1024;
  } else {              // B units
    gsrc0 = W3 + (size_t)(n0 + 32 * (w - 8) + lrow) * K + kc8;
    gsrc1 = W3 + (size_t)(n0 + 32 * (w - 8) + 16 + lrow) * K + kc8;
    ldst0 = 16384 + (w - 8) * 2048;
  }

  const int roff = (((l >> 4) ^ ((l >> 1) & 3)) << 4);
  const char* rdA = ldsb + (wr * 64 + (l & 15)) * 64 + roff;
  const char* rdB = ldsb + 16384 + (wc * 64 + (l & 15)) * 64 + roff;

  f32x4 acc[4][4] = {};

#define TILE_BODY(bo) {                                                        \
  bf16x8 a[4], b[4];                                                           \
  _Pragma("unroll") for (int m = 0; m < 4; ++m)                                \
    a[m] = *(const bf16x8*)(rdA + (bo) + m * 1024);                            \
  _Pragma("unroll") for (int n = 0; n < 4; ++n)                                \
    b[n] = *(const bf16x8*)(rdB + (bo) + n * 1024);                            \
  _Pragma("unroll") for (int m = 0; m < 4; ++m)                                \
    _Pragma("unroll") for (int n = 0; n < 4; ++n)                              \
      acc[m][n] = __builtin_amdgcn_mfma_f32_16x16x32_bf16(a[m], b[n], acc[m][n], 0, 0, 0); }

  gload16(gsrc0, ldsb + ldst0);               gload16(gsrc1, ldsb + ldst0 + 1024);
  gload16(gsrc0 + 32, ldsb + 32768 + ldst0);  gload16(gsrc1 + 32, ldsb + 32768 + ldst0 + 1024);
  gload16(gsrc0 + 64, ldsb + 65536 + ldst0);  gload16(gsrc1 + 64, ldsb + 65536 + ldst0 + 1024);
  const unsigned short* pg0 = gsrc0 + 96;
  const unsigned short* pg1 = gsrc1 + 96;
  WAITV(4);
  barrier_nodrain();

  int t = 0;
  for (; t + 3 < NK; ++t) {
    const int bo = (t & 3) << 15;
    const int bs = ((t + 3) & 3) << 15;
    gload16(pg0, ldsb + bs + ldst0);
    gload16(pg1, ldsb + bs + ldst0 + 1024);
    pg0 += 32; pg1 += 32;
    TILE_BODY(bo);
    WAITV(4); barrier_nodrain();
  }
  TILE_BODY((t & 3) << 15); WAITV(2); barrier_nodrain(); ++t;
  TILE_BODY((t & 3) << 15); WAITV(0); barrier_nodrain(); ++t;
  TILE_BODY((t & 3) << 15);
#undef TILE_BODY

  const int er = (l >> 4) * 4, ec = l & 15;
#pragma unroll
  for (int m = 0; m < 4; ++m)
#pragma unroll
    for (int n = 0; n < 4; ++n) {
      const int row = m0 + wr * 64 + m * 16 + er;
      const int col = n0 + wc * 64 + n * 16 + ec;
      float* ptr = Out + (size_t)row * N + col;
#pragma unroll
      for (int j = 0; j < 4; ++j) ptr[(size_t)j * N] = acc[m][n][j];
    }
}

// ---------------------------------------------------------------------------
extern "C" void kernel_launch(void* const* d_in, const int* in_sizes, int n_in,
                              void* d_out, int out_size, void* d_ws, size_t ws_size,
                              hipStream_t stream) {
  const float* x  = (const float*)d_in[0];   // [2,2048,4096] -> [4096][4096]
  const float* w1 = (const float*)d_in[1];   // [11008,4096]
  const float* w2 = (const float*)d_in[2];   // [11008,4096]
  const float* w3 = (const float*)d_in[3];   // [4096,11008]
  float* out = (float*)d_out;

  char* ws = (char*)d_ws;
  unsigned short* xb  = (unsigned short*)(ws);                // 32 MiB
  unsigned short* w1b = (unsigned short*)(ws + 33554432);     // 86 MiB
  unsigned short* w2b = (unsigned short*)(ws + 123731968);    // 86 MiB
  unsigned short* hb  = (unsigned short*)(ws + 213909504);    // 86 MiB

  const int N4X = 4096 * 4096 / 4;           // 4,194,304
  const int NW  = 11008 * 4096 / 4;          // 11,272,192

  const size_t W3B_OFF = 304087040;          // hb end
  const bool sep_w3 = (ws_size >= W3B_OFF + 90177536);

  if (sep_w3) {
    unsigned short* w3b = (unsigned short*)(ws + W3B_OFF);
    const int AUX_BLOCKS = (N4X + 3 * NW) / 256;
    k_aux_all4<<<AUX_BLOCKS, 256, 0, stream>>>(x, xb, N4X, w1, w1b, w2, w2b, w3, w3b, NW);
    k_gemm_dual_swiglu<<<1376, 1024, 0, stream>>>(xb, w1b, w2b, hb);
    k_gemm_out<<<256, 1024, 0, stream>>>(hb, w3b, out);
  } else {
    unsigned short* w3b = w1b;  // reuse after gemm1 (stream-ordered)
    const int AUX_BLOCKS = (N4X + 2 * NW) / 256;
    k_aux_all<<<AUX_BLOCKS, 256, 0, stream>>>(x, xb, N4X, w1, w1b, w2, w2b, NW);
    k_gemm_dual_swiglu<<<1376, 1024, 0, stream>>>(xb, w1b, w2b, hb);
    k_dequant_nf4<<<NW / 256, 256, 0, stream>>>(w3, w3b, NW);
    k_gemm_out<<<256, 1024, 0, stream>>>(hb, w3b, out);
  }
}

// Round 15
// 1213.337 us; speedup vs baseline: 1.0459x; 1.0235x over previous
//
#include <hip/hip_runtime.h>
#include <math.h>

typedef __attribute__((ext_vector_type(4))) float f32x4;
typedef __attribute__((ext_vector_type(8))) short bf16x8;

#define DI __device__ __forceinline__

DI unsigned short f32_to_bf16(float f) {
  unsigned int u = __float_as_uint(f);
  u += 0x7FFFu + ((u >> 16) & 1u);   // round-to-nearest-even
  return (unsigned short)(u >> 16);
}

static constexpr float kCode[16] = {
    -1.0f, -0.6961928009986877f, -0.5250730514526367f, -0.39491748809814453f,
    -0.28444138169288635f, -0.18477343022823334f, -0.09105003625154495f, 0.0f,
    0.07958029955625534f, 0.16093020141124725f, 0.24611230194568634f,
    0.33791524171829224f, 0.44070982933044434f, 0.5626170039176941f,
    0.7229568362236023f, 1.0f};

// ---------------------------------------------------------------------------
// NF4 quant-dequant (block=64): 16 lanes/block, float4/lane. Division-free.
// ---------------------------------------------------------------------------
DI void dequant_body(const float* __restrict__ in, unsigned short* __restrict__ out, int i) {
  f32x4 v = reinterpret_cast<const f32x4*>(in)[i];
  float am = fmaxf(fmaxf(fabsf(v.x), fabsf(v.y)), fmaxf(fabsf(v.z), fabsf(v.w)));
  am = fmaxf(am, __shfl_xor(am, 1));
  am = fmaxf(am, __shfl_xor(am, 2));
  am = fmaxf(am, __shfl_xor(am, 4));
  am = fmaxf(am, __shfl_xor(am, 8));
  const float scale = (am == 0.0f) ? 1.0f : am;
  float sb[15];
#pragma unroll
  for (int b = 0; b < 15; ++b)
    sb[b] = (0.5f * (kCode[b] + kCode[b + 1])) * scale;
  unsigned short o[4];
#pragma unroll
  for (int j = 0; j < 4; ++j) {
    const float vj = ((const float*)&v)[j];
    int idx = 0;
#pragma unroll
    for (int b = 0; b < 15; ++b)
      idx += (vj > sb[b]) ? 1 : 0;
    o[j] = f32_to_bf16(kCode[idx] * am);
  }
  reinterpret_cast<ushort4*>(out)[i] = make_ushort4(o[0], o[1], o[2], o[3]);
}

__global__ void __launch_bounds__(256) k_dequant_nf4(
    const float* __restrict__ in, unsigned short* __restrict__ out, int n4) {
  int i = blockIdx.x * 256 + threadIdx.x;
  if (i >= n4) return;
  dequant_body(in, out, i);
}

// merged aux (3-way): x convert + w1 + w2
__global__ void __launch_bounds__(256) k_aux_all(
    const float* __restrict__ x, unsigned short* __restrict__ xb, int n4x,
    const float* __restrict__ w1, unsigned short* __restrict__ w1b,
    const float* __restrict__ w2, unsigned short* __restrict__ w2b, int n4w) {
  int i = blockIdx.x * 256 + threadIdx.x;
  if (i < n4x) {
    f32x4 v = reinterpret_cast<const f32x4*>(x)[i];
    reinterpret_cast<ushort4*>(xb)[i] =
        make_ushort4(f32_to_bf16(v.x), f32_to_bf16(v.y), f32_to_bf16(v.z), f32_to_bf16(v.w));
  } else if (i < n4x + n4w) {
    dequant_body(w1, w1b, i - n4x);
  } else {
    dequant_body(w2, w2b, i - n4x - n4w);
  }
}

// ---------------------------------------------------------------------------
// GEMM helpers. BK=32, LDS rows = 64B. Element (r,k) at byte
//   r*64 + (((k>>3) ^ ((r>>1)&3))<<4) + (k&7)*2     (round-4 verified)
// Staging: global_load_lds linear; lane l of 1KB unit covers row 16u+(l>>2),
// k-chunk (l&3)^((l>>3)&3). Read: (rowbase+(l&15))*64 + ((l>>4)^((l>>1)&3))<<4
// -> conflict-free (SQ_LDS_BANK_CONFLICT == 0, rounds 4/5/8/9/11/12).
// ---------------------------------------------------------------------------
DI void gload16(const void* g, void* l) {
  __builtin_amdgcn_global_load_lds(
      (const __attribute__((address_space(1))) void*)g,
      (__attribute__((address_space(3))) void*)l, 16, 0, 0);
}

DI void barrier_nodrain() {
  asm volatile("" ::: "memory");
  __builtin_amdgcn_s_barrier();
  asm volatile("" ::: "memory");
}

#define WAITV(N) asm volatile("s_waitcnt vmcnt(" #N ")" ::: "memory")

DI float fast_silu(float g) {
  const float e = __builtin_amdgcn_exp2f(g * -1.442695041f);
  return g * __builtin_amdgcn_rcpf(1.0f + e);
}

// ---------------------------------------------------------------------------
// Fused dual GEMM + SwiGLU. BM=256, BN=128, BK=32, 16 waves (4/SIMD):
// waves 0-7 gate (B1), 8-15 up (B2); pair p = w&7 owns 64x64 at
// (wr=p>>1, wc=p&1). 4 LDS bufs x 32KB (A 16K | B1 8K | B2 8K),
// prefetch distance 3, counted vmcnt(4), hoisted wait-ladder.
// nt-major XCD swizzle. No setprio (m190: hurts loose schedules).
// ---------------------------------------------------------------------------
__global__ void __launch_bounds__(1024, 4) k_gemm_dual_swiglu(
    const unsigned short* __restrict__ X,
    const unsigned short* __restrict__ W1,
    const unsigned short* __restrict__ W2,
    unsigned short* __restrict__ H) {
  constexpr int K = 4096, N = 11008, NK = K / 32;
  __shared__ char ldsb[131072];

  const int tid = threadIdx.x;
  const int w = tid >> 6, l = tid & 63;

  // nt-major XCD swizzle: 1376 blocks = 8 XCD x 172; bijective.
  const int bid = blockIdx.x;
  const int xcd = bid & 7, ii = bid >> 3;   // ii in [0,172)
  const int nt = ii >> 1;                   // 0..85  (weight panel, slow)
  const int mt = xcd * 2 + (ii & 1);        // 0..15  (X panel, 2 per XCD)
  const int m0 = mt * 256, n0 = nt * 128;

  const int p = w & 7;
  const bool isGate = (w < 8);
  const int wr = p >> 1, wc = p & 1;

  // ---- staging: 32 1KB-units, 2 per wave (round-4 verified map) ----
  const int lrow = l >> 2;                              // 0..15
  const int kc8 = (((l & 3) ^ ((l >> 3) & 3)) << 3);    // elem col 0,8,16,24
  const unsigned short* gsrc0;
  const unsigned short* gsrc1;
  int ldst0;
  if (w < 8) {          // A units 2w, 2w+1 (rows m0+32w .. +31)
    gsrc0 = X + (size_t)(m0 + 32 * w + lrow) * K + kc8;
    gsrc1 = X + (size_t)(m0 + 32 * w + 16 + lrow) * K + kc8;
    ldst0 = 2 * w * 1024;
  } else if (w < 12) {  // B1 units
    gsrc0 = W1 + (size_t)(n0 + 32 * (w - 8) + lrow) * K + kc8;
    gsrc1 = W1 + (size_t)(n0 + 32 * (w - 8) + 16 + lrow) * K + kc8;
    ldst0 = 16384 + (w - 8) * 2048;
  } else {              // B2 units
    gsrc0 = W2 + (size_t)(n0 + 32 * (w - 12) + lrow) * K + kc8;
    gsrc1 = W2 + (size_t)(n0 + 32 * (w - 12) + 16 + lrow) * K + kc8;
    ldst0 = 24576 + (w - 12) * 2048;
  }

  // ---- read bases ----
  const int roff = (((l >> 4) ^ ((l >> 1) & 3)) << 4);
  const char* rdA = ldsb + (wr * 64 + (l & 15)) * 64 + roff;
  const char* rdB = ldsb + 16384 + (isGate ? 0 : 8192) +
                    (wc * 64 + (l & 15)) * 64 + roff;

  f32x4 acc[4][4] = {};

#define TILE_BODY(bo) {                                                        \
  bf16x8 a[4], b[4];                                                           \
  _Pragma("unroll") for (int m = 0; m < 4; ++m)                                \
    a[m] = *(const bf16x8*)(rdA + (bo) + m * 1024);                            \
  _Pragma("unroll") for (int n = 0; n < 4; ++n)                                \
    b[n] = *(const bf16x8*)(rdB + (bo) + n * 1024);                            \
  _Pragma("unroll") for (int m = 0; m < 4; ++m)                                \
    _Pragma("unroll") for (int n = 0; n < 4; ++n)                              \
      acc[m][n] = __builtin_amdgcn_mfma_f32_16x16x32_bf16(a[m], b[n], acc[m][n], 0, 0, 0); }

  // prologue: stage tiles 0,1,2
  gload16(gsrc0, ldsb + ldst0);               gload16(gsrc1, ldsb + ldst0 + 1024);
  gload16(gsrc0 + 32, ldsb + 32768 + ldst0);  gload16(gsrc1 + 32, ldsb + 32768 + ldst0 + 1024);
  gload16(gsrc0 + 64, ldsb + 65536 + ldst0);  gload16(gsrc1 + 64, ldsb + 65536 + ldst0 + 1024);
  const unsigned short* pg0 = gsrc0 + 96;     // tile t+3 cursor
  const unsigned short* pg1 = gsrc1 + 96;
  WAITV(4);
  barrier_nodrain();

  int t = 0;
  for (; t + 3 < NK; ++t) {              // branchless main loop
    const int bo = (t & 3) << 15;
    const int bs = ((t + 3) & 3) << 15;
    gload16(pg0, ldsb + bs + ldst0);
    gload16(pg1, ldsb + bs + ldst0 + 1024);
    pg0 += 32; pg1 += 32;
    TILE_BODY(bo);
    WAITV(4); barrier_nodrain();
  }
  // tail: t = NK-3, NK-2, NK-1 (no staging)
  TILE_BODY((t & 3) << 15); WAITV(2); barrier_nodrain(); ++t;
  TILE_BODY((t & 3) << 15); WAITV(0); barrier_nodrain(); ++t;
  TILE_BODY((t & 3) << 15);
#undef TILE_BODY

  // ---- epilogue: pairwise f32 exchange (m-split), balanced stores ----
  barrier_nodrain();  // staging LDS now dead for ALL waves
  char* xch = ldsb + p * 16384 + (isGate ? 0 : 8192);
  // gate writes its m=2,3 frags; up writes its m=0,1 frags
#pragma unroll
  for (int m2 = 0; m2 < 2; ++m2)
#pragma unroll
    for (int n = 0; n < 4; ++n) {
      const int m = isGate ? (m2 + 2) : m2;
      *(f32x4*)(xch + ((m2 * 4 + n) * 64 + l) * 16) = acc[m][n];
    }
  barrier_nodrain();
  const char* oxch = ldsb + p * 16384 + (isGate ? 8192 : 0);
  const int er = (l >> 4) * 4, ec = l & 15;
#pragma unroll
  for (int m2 = 0; m2 < 2; ++m2)
#pragma unroll
    for (int n = 0; n < 4; ++n) {
      const int mk = isGate ? m2 : (m2 + 2);   // rows this wave stores
      f32x4 other = *(const f32x4*)(oxch + ((m2 * 4 + n) * 64 + l) * 16);
#pragma unroll
      for (int j = 0; j < 4; ++j) {
        const float g_ = isGate ? acc[mk][n][j] : other[j];
        const float u_ = isGate ? other[j] : acc[mk][n][j];
        const float s = fast_silu(g_);
        const int row = m0 + wr * 64 + mk * 16 + er + j;
        const int col = n0 + wc * 64 + n * 16 + ec;
        H[(size_t)row * N + col] = f32_to_bf16(s * u_);
      }
    }
}

// ---------------------------------------------------------------------------
// Output GEMM. BM=BN=256, BK=32, 16 waves (4M x 4N), per-wave 64x64.
// 4 LDS bufs x 32KB (A 16K | B 16K), prefetch 3, hoisted ladder.
// nt-major XCD swizzle. No setprio. H x W3^T -> Out f32.
// ---------------------------------------------------------------------------
__global__ void __launch_bounds__(1024, 4) k_gemm_out(
    const unsigned short* __restrict__ Hm,
    const unsigned short* __restrict__ W3,
    float* __restrict__ Out) {
  constexpr int K = 11008, N = 4096, NK = K / 32;   // NK = 344
  __shared__ char ldsb[131072];

  const int tid = threadIdx.x;
  const int w = tid >> 6, l = tid & 63;

  const int bid = blockIdx.x;
  const int xcd = bid & 7, ii = bid >> 3;   // ii in [0,32)
  const int nt = ii >> 1;                   // 0..15
  const int mt = xcd * 2 + (ii & 1);        // 0..15
  const int m0 = mt * 256, n0 = nt * 256;

  const int wr = w >> 2, wc = w & 3;

  const int lrow = l >> 2;
  const int kc8 = (((l & 3) ^ ((l >> 3) & 3)) << 3);
  const unsigned short* gsrc0;
  const unsigned short* gsrc1;
  int ldst0;
  if (w < 8) {          // A units
    gsrc0 = Hm + (size_t)(m0 + 32 * w + lrow) * K + kc8;
    gsrc1 = Hm + (size_t)(m0 + 32 * w + 16 + lrow) * K + kc8;
    ldst0 = 2 * w * 1024;
  } else {              // B units
    gsrc0 = W3 + (size_t)(n0 + 32 * (w - 8) + lrow) * K + kc8;
    gsrc1 = W3 + (size_t)(n0 + 32 * (w - 8) + 16 + lrow) * K + kc8;
    ldst0 = 16384 + (w - 8) * 2048;
  }

  const int roff = (((l >> 4) ^ ((l >> 1) & 3)) << 4);
  const char* rdA = ldsb + (wr * 64 + (l & 15)) * 64 + roff;
  const char* rdB = ldsb + 16384 + (wc * 64 + (l & 15)) * 64 + roff;

  f32x4 acc[4][4] = {};

#define TILE_BODY(bo) {                                                        \
  bf16x8 a[4], b[4];                                                           \
  _Pragma("unroll") for (int m = 0; m < 4; ++m)                                \
    a[m] = *(const bf16x8*)(rdA + (bo) + m * 1024);                            \
  _Pragma("unroll") for (int n = 0; n < 4; ++n)                                \
    b[n] = *(const bf16x8*)(rdB + (bo) + n * 1024);                            \
  _Pragma("unroll") for (int m = 0; m < 4; ++m)                                \
    _Pragma("unroll") for (int n = 0; n < 4; ++n)                              \
      acc[m][n] = __builtin_amdgcn_mfma_f32_16x16x32_bf16(a[m], b[n], acc[m][n], 0, 0, 0); }

  gload16(gsrc0, ldsb + ldst0);               gload16(gsrc1, ldsb + ldst0 + 1024);
  gload16(gsrc0 + 32, ldsb + 32768 + ldst0);  gload16(gsrc1 + 32, ldsb + 32768 + ldst0 + 1024);
  gload16(gsrc0 + 64, ldsb + 65536 + ldst0);  gload16(gsrc1 + 64, ldsb + 65536 + ldst0 + 1024);
  const unsigned short* pg0 = gsrc0 + 96;
  const unsigned short* pg1 = gsrc1 + 96;
  WAITV(4);
  barrier_nodrain();

  int t = 0;
  for (; t + 3 < NK; ++t) {
    const int bo = (t & 3) << 15;
    const int bs = ((t + 3) & 3) << 15;
    gload16(pg0, ldsb + bs + ldst0);
    gload16(pg1, ldsb + bs + ldst0 + 1024);
    pg0 += 32; pg1 += 32;
    TILE_BODY(bo);
    WAITV(4); barrier_nodrain();
  }
  TILE_BODY((t & 3) << 15); WAITV(2); barrier_nodrain(); ++t;
  TILE_BODY((t & 3) << 15); WAITV(0); barrier_nodrain(); ++t;
  TILE_BODY((t & 3) << 15);
#undef TILE_BODY

  const int er = (l >> 4) * 4, ec = l & 15;
#pragma unroll
  for (int m = 0; m < 4; ++m)
#pragma unroll
    for (int n = 0; n < 4; ++n) {
      const int row = m0 + wr * 64 + m * 16 + er;
      const int col = n0 + wc * 64 + n * 16 + ec;
      float* ptr = Out + (size_t)row * N + col;
#pragma unroll
      for (int j = 0; j < 4; ++j) ptr[(size_t)j * N] = acc[m][n][j];
    }
}

// ---------------------------------------------------------------------------
extern "C" void kernel_launch(void* const* d_in, const int* in_sizes, int n_in,
                              void* d_out, int out_size, void* d_ws, size_t ws_size,
                              hipStream_t stream) {
  const float* x  = (const float*)d_in[0];   // [2,2048,4096] -> [4096][4096]
  const float* w1 = (const float*)d_in[1];   // [11008,4096]
  const float* w2 = (const float*)d_in[2];   // [11008,4096]
  const float* w3 = (const float*)d_in[3];   // [4096,11008]
  float* out = (float*)d_out;

  char* ws = (char*)d_ws;
  unsigned short* xb  = (unsigned short*)(ws);                // 32 MiB
  unsigned short* w1b = (unsigned short*)(ws + 33554432);     // 86 MiB
  unsigned short* w2b = (unsigned short*)(ws + 123731968);    // 86 MiB
  unsigned short* hb  = (unsigned short*)(ws + 213909504);    // 86 MiB
  unsigned short* w3b = w1b;  // reuse after gemm1 (stream-ordered)

  const int N4X = 4096 * 4096 / 4;           // 4,194,304
  const int NW  = 11008 * 4096 / 4;          // 11,272,192
  const int AUX_BLOCKS = (N4X + 2 * NW) / 256;
  k_aux_all<<<AUX_BLOCKS, 256, 0, stream>>>(x, xb, N4X, w1, w1b, w2, w2b, NW);

  // gate/up + SwiGLU -> h  (M=4096, N=11008, K=4096)
  k_gemm_dual_swiglu<<<1376, 1024, 0, stream>>>(xb, w1b, w2b, hb);

  k_dequant_nf4<<<NW / 256, 256, 0, stream>>>(w3, w3b, NW);

  // out = h . w3^T  (M=4096, N=4096, K=11008)
  k_gemm_out<<<256, 1024, 0, stream>>>(hb, w3b, out);
}